// Round 7
// baseline (991.322 us; speedup 1.0000x reference)
//
#include <hip/hip_runtime.h>
#include <hip/hip_bf16.h>
#include <hip/hip_cooperative_groups.h>

namespace cg = cooperative_groups;

typedef unsigned short u16;
typedef unsigned int   u32;

#define N_NODES 10000
#define N_EDGES 160000
#define HDIM    512
#define KDIM    1024
#define NPAD    10112   // 79 * 128
#define NTILES  632     // 158 m-tiles(64 rows) x 4 n-panels(128 cols)

typedef __attribute__((ext_vector_type(8))) __bf16 bf16x8;
typedef __attribute__((ext_vector_type(4))) float  f32x4;

__device__ __forceinline__ float bflo(u32 v){ return __builtin_bit_cast(float, v << 16); }
__device__ __forceinline__ float bfhi(u32 v){ return __builtin_bit_cast(float, v & 0xffff0000u); }
__device__ __forceinline__ u16   f2bf(float f){ __hip_bfloat16 h = __float2bfloat16(f); return __builtin_bit_cast(u16, h); }

// ---------------- CSR build ----------------
__global__ void k_hist(const int* __restrict__ dst, int* __restrict__ cnt){
  int e = blockIdx.x*256 + threadIdx.x;
  if (e < N_EDGES) atomicAdd(&cnt[dst[e]], 1);
}

__global__ __launch_bounds__(1024) void k_scan(const int* __restrict__ cnt, int* __restrict__ row_ptr,
                                               int* __restrict__ cursor, float* __restrict__ inv_deg){
  __shared__ int part[1024];
  int t = threadIdx.x;
  int base = t*10;
  int local[10]; int s = 0;
  for (int i=0;i<10;i++){
    int idx = base+i;
    int v = (idx < N_NODES) ? cnt[idx] : 0;
    local[i] = s; s += v;
  }
  part[t] = s;
  __syncthreads();
  for (int off=1; off<1024; off<<=1){
    int v = (t>=off) ? part[t-off] : 0;
    __syncthreads();
    part[t] += v;
    __syncthreads();
  }
  int prev = (t==0) ? 0 : part[t-1];
  for (int i=0;i<10;i++){
    int idx = base+i;
    if (idx < N_NODES){
      int rp = prev + local[i];
      row_ptr[idx] = rp; cursor[idx] = rp;
      int c = cnt[idx];
      inv_deg[idx] = 1.0f / (float)(c > 0 ? c : 1);
    }
  }
  if (t==1023) row_ptr[N_NODES] = part[1023];
}

__global__ void k_fill(const int* __restrict__ src, const int* __restrict__ dst,
                       int* __restrict__ cursor, int* __restrict__ csr_src){
  int e = blockIdx.x*256 + threadIdx.x;
  if (e < N_EDGES){
    int pos = atomicAdd(&cursor[dst[e]], 1);
    csr_src[pos] = src[e];
  }
}

// ---------------- prep: wcat (fp32->bf16 concat) + copy_x + zero scratch ----------------
#define NZERO 14656   // cnt(10048) + stats(4096) + bias0(512)
__global__ __launch_bounds__(256) void k_prep(const float* __restrict__ wpr, const float* __restrict__ wpo,
                                              const float* __restrict__ wrel, const float* __restrict__ wroot,
                                              const float* __restrict__ wfr, const float* __restrict__ wfo,
                                              const float* __restrict__ x,
                                              u16* __restrict__ Wcat, u16* __restrict__ Wfin,
                                              u16* __restrict__ A, u32* __restrict__ zreg){
  int b = blockIdx.x, t = threadIdx.x;
  if (b < 4096){
    int i = b*256 + t;
    int lyr = i >> 18;
    int r   = i & 262143;
    int o = r >> 9, k = r & 511;
    const float* R = (lyr==0) ? wpr : wrel  + (size_t)(lyr-1)*262144;
    const float* O = (lyr==0) ? wpo : wroot + (size_t)(lyr-1)*262144;
    Wcat[(size_t)lyr*524288 + (size_t)o*KDIM + k]        = f2bf(R[r]);
    Wcat[(size_t)lyr*524288 + (size_t)o*KDIM + HDIM + k] = f2bf(O[r]);
    if (i < 10*512){
      int oo = i >> 9, kk = i & 511;
      Wfin[oo*KDIM + kk]        = f2bf(wfr[i]);
      Wfin[oo*KDIM + HDIM + kk] = f2bf(wfo[i]);
    }
  } else if (b < 9096){
    int c = (b-4096)*256 + t;
    int n = c >> 7, o = (c & 127)*4;
    float4 v = *(const float4*)(x + (size_t)n*HDIM + o);
    ushort4 bb;
    bb.x = f2bf(v.x); bb.y = f2bf(v.y); bb.z = f2bf(v.z); bb.w = f2bf(v.w);
    *(ushort4*)(A + (size_t)n*KDIM + HDIM + o) = bb;
  } else {
    int i = (b-9096)*256 + t;
    if (i < NZERO) zreg[i] = 0u;
  }
}

// ================= shared device phases =================

__device__ __forceinline__ void agg_node(int n, const u16* __restrict__ Abuf,
                                         const int* __restrict__ row_ptr, const int* __restrict__ cnt,
                                         const int* __restrict__ csr_src, const float* __restrict__ inv_deg,
                                         u16* __restrict__ Aleft, char* smem){
  float (*red)[512] = (float(*)[512])smem;
  int t = threadIdx.x, l = t & 63, w = t >> 6;
  int start = row_ptr[n], num = cnt[n];
  float acc[8];
  #pragma unroll
  for (int i=0;i<8;i++) acc[i]=0.f;

  int j = w;
  while (j + 4 < num){
    int s0 = csr_src[start + j];
    int s1 = csr_src[start + j + 4];
    uint4 v0 = *(const uint4*)(Abuf + (size_t)s0*KDIM + HDIM + l*8);
    uint4 v1 = *(const uint4*)(Abuf + (size_t)s1*KDIM + HDIM + l*8);
    acc[0]+=bflo(v0.x); acc[1]+=bfhi(v0.x);
    acc[2]+=bflo(v0.y); acc[3]+=bfhi(v0.y);
    acc[4]+=bflo(v0.z); acc[5]+=bfhi(v0.z);
    acc[6]+=bflo(v0.w); acc[7]+=bfhi(v0.w);
    acc[0]+=bflo(v1.x); acc[1]+=bfhi(v1.x);
    acc[2]+=bflo(v1.y); acc[3]+=bfhi(v1.y);
    acc[4]+=bflo(v1.z); acc[5]+=bfhi(v1.z);
    acc[6]+=bflo(v1.w); acc[7]+=bfhi(v1.w);
    j += 8;
  }
  if (j < num){
    int s = csr_src[start + j];
    uint4 v = *(const uint4*)(Abuf + (size_t)s*KDIM + HDIM + l*8);
    acc[0]+=bflo(v.x); acc[1]+=bfhi(v.x);
    acc[2]+=bflo(v.y); acc[3]+=bfhi(v.y);
    acc[4]+=bflo(v.z); acc[5]+=bfhi(v.z);
    acc[6]+=bflo(v.w); acc[7]+=bfhi(v.w);
  }
  #pragma unroll
  for (int i=0;i<8;i++) red[w][l*8+i] = acc[i];
  __syncthreads();
  float id = inv_deg[n];
  int c = t*2;
  float a0 = (red[0][c]  +red[1][c]  +red[2][c]  +red[3][c]  ) * id;
  float a1 = (red[0][c+1]+red[1][c+1]+red[2][c+1]+red[3][c+1]) * id;
  u32 o = ((u32)f2bf(a1) << 16) | (u32)f2bf(a0);
  *(u32*)(Aleft + (size_t)n*KDIM + c) = o;
  __syncthreads();
}

__device__ __forceinline__ void gemm_tile(int id, const u16* __restrict__ A, const u16* __restrict__ W,
                                          const float* __restrict__ bias,
                                          u16* __restrict__ Hout, float* __restrict__ stats, char* smem){
  u16*   As    = (u16*)smem;              // 4096 B
  u16*   Bs    = (u16*)(smem + 4096);     // 8192 B
  float* red_s = (float*)(smem + 12288);  // 1024 B
  float* red_q = (float*)(smem + 13312);  // 1024 B
  const int t  = threadIdx.x;
  const int l  = t & 63;
  const int wv = t >> 6;
  const int wm = wv >> 1, wn = wv & 1;
  const int m0 = (id >> 2) * 64;
  const int n0 = (id & 3) * 128;

  const int c1 = t + 256;
  const size_t gA  = (size_t)(m0 + (t>>2))*KDIM + ((t&3)*8);
  const size_t gB0 = (size_t)(n0 + (t>>2))*KDIM + ((t&3)*8);
  const size_t gB1 = (size_t)(n0 + (c1>>2))*KDIM + ((c1&3)*8);

  f32x4 acc[2][4];
  #pragma unroll
  for (int i=0;i<2;i++)
    #pragma unroll
    for (int j=0;j<4;j++)
      acc[i][j] = f32x4{0.f,0.f,0.f,0.f};

  const int aoff = (wm*32 + (l&15))*32 + (l>>4)*8;
  const int boff = (wn*64 + (l&15))*32 + (l>>4)*8;

  for (int k0 = 0; k0 < KDIM; k0 += 32){
    __builtin_amdgcn_global_load_lds((const __attribute__((address_space(1))) void*)(A + gA + k0),
                                     (__attribute__((address_space(3))) void*)(As + t*8), 16, 0, 0);
    __builtin_amdgcn_global_load_lds((const __attribute__((address_space(1))) void*)(W + gB0 + k0),
                                     (__attribute__((address_space(3))) void*)(Bs + t*8), 16, 0, 0);
    __builtin_amdgcn_global_load_lds((const __attribute__((address_space(1))) void*)(W + gB1 + k0),
                                     (__attribute__((address_space(3))) void*)(Bs + c1*8), 16, 0, 0);
    __syncthreads();
    bf16x8 af[2], bfr[4];
    af[0] = *(const bf16x8*)(As + aoff);
    af[1] = *(const bf16x8*)(As + aoff + 16*32);
    #pragma unroll
    for (int nt=0; nt<4; nt++)
      bfr[nt] = *(const bf16x8*)(Bs + boff + nt*16*32);
    #pragma unroll
    for (int mt=0; mt<2; mt++)
      #pragma unroll
      for (int nt=0; nt<4; nt++)
        acc[mt][nt] = __builtin_amdgcn_mfma_f32_16x16x32_bf16(af[mt], bfr[nt], acc[mt][nt], 0, 0, 0);
    __syncthreads();
  }

  float bi[4], sc[4], qc[4];
  #pragma unroll
  for (int nt=0; nt<4; nt++){
    bi[nt] = bias[n0 + wn*64 + nt*16 + (l & 15)];
    sc[nt] = 0.f; qc[nt] = 0.f;
  }
  #pragma unroll
  for (int nt=0; nt<4; nt++){
    const int col = n0 + wn*64 + nt*16 + (l & 15);
    #pragma unroll
    for (int mt=0; mt<2; mt++){
      #pragma unroll
      for (int r=0; r<4; r++){
        const int row = m0 + wm*32 + mt*16 + (l>>4)*4 + r;
        if (row < N_NODES){
          float v = acc[mt][nt][r] + bi[nt];
          v = v > 0.f ? v : 0.f;
          sc[nt] += v; qc[nt] += v*v;
          Hout[(size_t)row*KDIM + HDIM + col] = f2bf(v);
        }
      }
    }
  }
  #pragma unroll
  for (int nt=0; nt<4; nt++){
    float s = sc[nt], q = qc[nt];
    s += __shfl_xor(s, 16); s += __shfl_xor(s, 32);
    q += __shfl_xor(q, 16); q += __shfl_xor(q, 32);
    if (l < 16){
      red_s[wm*128 + wn*64 + nt*16 + l] = s;
      red_q[wm*128 + wn*64 + nt*16 + l] = q;
    }
  }
  __syncthreads();
  if (t < 128){
    atomicAdd(&stats[n0 + t],       red_s[t] + red_s[128 + t]);
    atomicAdd(&stats[512 + n0 + t], red_q[t] + red_q[128 + t]);
  }
  __syncthreads();
}

__device__ __forceinline__ void wscale_row(int o, const u16* __restrict__ Wsrc, const float* __restrict__ stats,
                                           const float* __restrict__ gamma, const float* __restrict__ beta,
                                           int layer, u16* __restrict__ Wdst, float* __restrict__ biasOut,
                                           char* smem){
  float* wred = (float*)smem;
  int t = threadIdx.x, l = t & 63, w = t >> 6;
  int k = t*4;
  int fk = k & 511;
  float a[4], b[4];
  #pragma unroll
  for (int i=0;i<4;i++){
    int f = fk + i;
    float mu  = stats[f] * (1.f/N_NODES);
    float var = stats[512+f] * (1.f/N_NODES) - mu*mu;
    float rs  = rsqrtf(var + 1e-5f);
    float g = gamma[layer*512+f];
    a[i] = g*rs;
    b[i] = beta[layer*512+f] - mu*a[i];
  }
  const u16* row = Wsrc + (size_t)o*KDIM;
  uint2 v = *(const uint2*)(row + k);
  float f0 = bflo(v.x), f1 = bfhi(v.x), f2 = bflo(v.y), f3 = bfhi(v.y);
  u16 od[4];
  od[0]=f2bf(f0*a[0]); od[1]=f2bf(f1*a[1]); od[2]=f2bf(f2*a[2]); od[3]=f2bf(f3*a[3]);
  *(ushort4*)(Wdst + (size_t)o*KDIM + k) = *(ushort4*)od;
  float bsum = f0*b[0] + f1*b[1] + f2*b[2] + f3*b[3];
  #pragma unroll
  for (int off=32; off; off>>=1) bsum += __shfl_down(bsum, off);
  if (l==0) wred[w] = bsum;
  __syncthreads();
  if (t==0) biasOut[o] = wred[0]+wred[1]+wred[2]+wred[3];
  __syncthreads();
}

__device__ __forceinline__ void final_node(int n, const u16* __restrict__ A, const u16* __restrict__ Wf,
                                           const float* __restrict__ biasF, float* __restrict__ out){
  int l = threadIdx.x & 63;
  float acc[10];
  #pragma unroll
  for (int c=0;c<10;c++) acc[c]=0.f;
  const u16* An = A + (size_t)n*KDIM;
  #pragma unroll
  for (int half=0; half<KDIM; half+=512){
    uint4 va = *(const uint4*)(An + half + l*8);
    float a0=bflo(va.x),a1=bfhi(va.x),a2=bflo(va.y),a3=bfhi(va.y);
    float a4=bflo(va.z),a5=bfhi(va.z),a6=bflo(va.w),a7=bfhi(va.w);
    #pragma unroll
    for (int c=0;c<10;c++){
      uint4 vw = *(const uint4*)(Wf + (size_t)c*KDIM + half + l*8);
      acc[c] += a0*bflo(vw.x)+a1*bfhi(vw.x)+a2*bflo(vw.y)+a3*bfhi(vw.y)
              + a4*bflo(vw.z)+a5*bfhi(vw.z)+a6*bflo(vw.w)+a7*bfhi(vw.w);
    }
  }
  #pragma unroll
  for (int c=0;c<10;c++)
    #pragma unroll
    for (int off=32; off; off>>=1)
      acc[c] += __shfl_down(acc[c], off);
  if (l == 0){
    #pragma unroll
    for (int c=0;c<10;c++) acc[c] += biasF[c];
    float m = acc[0];
    #pragma unroll
    for (int c=1;c<10;c++) m = fmaxf(m, acc[c]);
    float s = 0.f;
    #pragma unroll
    for (int c=0;c<10;c++) s += expf(acc[c]-m);
    float lse = m + logf(s);
    #pragma unroll
    for (int c=0;c<10;c++) out[n*10+c] = acc[c]-lse;
  }
}

// ================= standalone kernels (fallback path) =================
__global__ __launch_bounds__(256) void k_agg(const u16* __restrict__ Abuf,
                                             const int* __restrict__ row_ptr, const int* __restrict__ cnt,
                                             const int* __restrict__ csr, const float* __restrict__ inv_deg,
                                             u16* __restrict__ Aleft){
  __shared__ __align__(16) char smem[8192];
  agg_node(blockIdx.x, Abuf, row_ptr, cnt, csr, inv_deg, Aleft, smem);
}

__global__ __launch_bounds__(256) void k_gemm(const u16* __restrict__ A, const u16* __restrict__ W,
                                              const float* __restrict__ bias,
                                              u16* __restrict__ Hout, float* __restrict__ stats){
  __shared__ __align__(16) char smem[14336];
  gemm_tile(blockIdx.x, A, W, bias, Hout, stats, smem);
}

__global__ __launch_bounds__(256) void k_wscale(const u16* __restrict__ Wsrc, const float* __restrict__ stats,
                                                const float* __restrict__ gamma, const float* __restrict__ beta,
                                                int layer, u16* __restrict__ Wdst, float* __restrict__ biasOut){
  __shared__ __align__(16) char smem[64];
  wscale_row(blockIdx.x, Wsrc, stats, gamma, beta, layer, Wdst, biasOut, smem);
}

__global__ __launch_bounds__(256) void k_final(const u16* __restrict__ A, const u16* __restrict__ Wf,
                                               const float* __restrict__ biasF, float* __restrict__ out){
  int n = blockIdx.x*4 + (threadIdx.x >> 6);
  if (n < N_NODES) final_node(n, A, Wf, biasF, out);
}

// ================= cooperative mega-kernel (grid-size agnostic) =================
__global__ __launch_bounds__(256, 2) void k_mega(
    const u16* __restrict__ Wcat, const u16* __restrict__ Wfin,
    u16* __restrict__ Wsc, u16* __restrict__ WfinSc,
    u16* __restrict__ A0, u16* __restrict__ A1,
    const int* __restrict__ row_ptr, const int* __restrict__ cnt,
    const int* __restrict__ csr, const float* __restrict__ inv_deg,
    float* __restrict__ stats, const float* __restrict__ bias0,
    float* __restrict__ biasN, float* __restrict__ biasF,
    const float* __restrict__ gamma, const float* __restrict__ beta,
    float* __restrict__ out){
  cg::grid_group grid = cg::this_grid();
  __shared__ __align__(16) char smem[14336];
  const int bid = blockIdx.x;
  const int nb  = gridDim.x;

  for (int n = bid; n < N_NODES; n += nb)
    agg_node(n, A0, row_ptr, cnt, csr, inv_deg, A0, smem);
  grid.sync();

  u16* Ain = A0; u16* Aout = A1;
  for (int lyr = 0; lyr < 4; lyr++){
    const u16* Wthis   = (lyr==0) ? Wcat : Wsc;
    const float* bthis = (lyr==0) ? bias0 : biasN;
    float* st = stats + lyr*1024;

    for (int tile = bid; tile < NTILES; tile += nb)
      gemm_tile(tile, Ain, Wthis, bthis, Aout, st, smem);
    grid.sync();

    if (lyr < 3){
      for (int o = bid; o < 512; o += nb)
        wscale_row(o, Wcat + (size_t)(lyr+1)*HDIM*KDIM, st, gamma, beta, lyr, Wsc, biasN, smem);
    } else {
      for (int o = bid; o < 10; o += nb)
        wscale_row(o, Wfin, st, gamma, beta, lyr, WfinSc, biasF, smem);
    }
    __syncthreads();
    for (int n = bid; n < N_NODES; n += nb)
      agg_node(n, Aout, row_ptr, cnt, csr, inv_deg, Aout, smem);
    grid.sync();

    u16* tmp = Ain; Ain = Aout; Aout = tmp;
  }

  int wv = threadIdx.x >> 6;
  for (int n = bid*4 + wv; n < N_NODES; n += nb*4)
    final_node(n, Ain, WfinSc, biasF, out);
}

extern "C" void kernel_launch(void* const* d_in, const int* in_sizes, int n_in,
                              void* d_out, int out_size, void* d_ws, size_t ws_size,
                              hipStream_t stream){
  (void)in_sizes; (void)n_in; (void)out_size; (void)ws_size;
  const float* x     = (const float*)d_in[0];
  const int*   eidx  = (const int*)d_in[1];
  const float* wpr   = (const float*)d_in[2];
  const float* wpo   = (const float*)d_in[3];
  const float* wrel  = (const float*)d_in[4];
  const float* wroot = (const float*)d_in[5];
  const float* gamma = (const float*)d_in[6];
  const float* beta  = (const float*)d_in[7];
  const float* wfr   = (const float*)d_in[8];
  const float* wfo   = (const float*)d_in[9];
  const int* src  = eidx;
  const int* dstv = eidx + N_EDGES;

  char* p = (char*)d_ws;
  auto carve = [&](size_t b){ char* q = p; p += (b + 255) & ~(size_t)255; return q; };
  u16*  A0      = (u16*)carve((size_t)NPAD*KDIM*2);
  u16*  A1      = (u16*)carve((size_t)NPAD*KDIM*2);
  u16*  Wcat    = (u16*)carve((size_t)4*HDIM*KDIM*2);
  u16*  Wfin    = (u16*)carve((size_t)10*KDIM*2);
  u16*  Wsc     = (u16*)carve((size_t)HDIM*KDIM*2);
  u16*  WfinSc  = (u16*)carve((size_t)10*KDIM*2);
  int*   zreg   = (int*)carve((size_t)NZERO*4);
  int*   cnt    = zreg;
  float* stats  = (float*)(zreg + 10048);
  float* bias0  = (float*)(zreg + 10048 + 4096);
  int*  row_ptr = (int*)carve((N_NODES+1)*4);
  int*  cursor  = (int*)carve(N_NODES*4);
  int*  csr     = (int*)carve(N_EDGES*4);
  float* inv_deg= (float*)carve(N_NODES*4);
  float* biasN  = (float*)carve(512*4);
  float* biasF  = (float*)carve(512*4);
  float* outp   = (float*)d_out;

  k_prep<<<9154, 256, 0, stream>>>(wpr, wpo, wrel, wroot, wfr, wfo, x, Wcat, Wfin, A0, (u32*)zreg);
  k_hist<<<(N_EDGES+255)/256, 256, 0, stream>>>(dstv, cnt);
  k_scan<<<1, 1024, 0, stream>>>(cnt, row_ptr, cursor, inv_deg);
  k_fill<<<(N_EDGES+255)/256, 256, 0, stream>>>(src, dstv, cursor, csr);

  // cooperative path, sized by actual occupancy
  int maxb = 0;
  hipError_t qe = hipOccupancyMaxActiveBlocksPerMultiprocessor(&maxb, k_mega, 256, 0);
  int grid = (qe == hipSuccess && maxb > 0) ? (maxb * 256) : 0;
  if (grid > 512) grid = 512;

  hipError_t le = hipErrorUnknown;
  if (grid > 0){
    void* args[] = { (void*)&Wcat, (void*)&Wfin, (void*)&Wsc, (void*)&WfinSc,
                     (void*)&A0, (void*)&A1,
                     (void*)&row_ptr, (void*)&cnt, (void*)&csr, (void*)&inv_deg,
                     (void*)&stats, (void*)&bias0, (void*)&biasN, (void*)&biasF,
                     (void*)&gamma, (void*)&beta, (void*)&outp };
    le = hipLaunchCooperativeKernel((const void*)k_mega, dim3(grid), dim3(256), args, 0, stream);
  }

  if (le != hipSuccess){
    // fallback: proven R5 multi-launch path (identical arithmetic)
    k_agg<<<N_NODES, 256, 0, stream>>>(A0, row_ptr, cnt, csr, inv_deg, A0);
    u16* Ain = A0; u16* Aout = A1;
    for (int lyr=0; lyr<4; lyr++){
      const u16* Wthis = (lyr==0) ? Wcat : Wsc;
      const float* bthis = (lyr==0) ? bias0 : biasN;
      k_gemm<<<NTILES, 256, 0, stream>>>(Ain, Wthis, bthis, Aout, stats + lyr*1024);
      if (lyr < 3)
        k_wscale<<<512, 256, 0, stream>>>(Wcat + (size_t)(lyr+1)*HDIM*KDIM, stats + lyr*1024,
                                          gamma, beta, lyr, Wsc, biasN);
      else
        k_wscale<<<10, 256, 0, stream>>>(Wfin, stats + lyr*1024, gamma, beta, lyr, WfinSc, biasF);
      k_agg<<<N_NODES, 256, 0, stream>>>(Aout, row_ptr, cnt, csr, inv_deg, Aout);
      u16* tmp = Ain; Ain = Aout; Aout = tmp;
    }
    k_final<<<2500, 256, 0, stream>>>(Ain, WfinSc, biasF, outp);
  }
}

// Round 8
// 369.579 us; speedup vs baseline: 2.6823x; 2.6823x over previous
//
#include <hip/hip_runtime.h>
#include <hip/hip_bf16.h>

typedef unsigned short u16;
typedef unsigned int   u32;

#define N_NODES 10000
#define N_EDGES 160000
#define HDIM    512
#define KDIM    1024
#define NPAD    10112   // 79 * 128
#define NTILES  632     // 158 m-tiles(64 rows) x 4 n-panels(128 cols)

typedef __attribute__((ext_vector_type(8))) __bf16 bf16x8;
typedef __attribute__((ext_vector_type(4))) float  f32x4;

__device__ __forceinline__ float bflo(u32 v){ return __builtin_bit_cast(float, v << 16); }
__device__ __forceinline__ float bfhi(u32 v){ return __builtin_bit_cast(float, v & 0xffff0000u); }
__device__ __forceinline__ u16   f2bf(float f){ __hip_bfloat16 h = __float2bfloat16(f); return __builtin_bit_cast(u16, h); }

// ---------------- CSR build ----------------
__global__ void k_hist(const int* __restrict__ dst, int* __restrict__ cnt){
  int e = blockIdx.x*256 + threadIdx.x;
  if (e < N_EDGES) atomicAdd(&cnt[dst[e]], 1);
}

__global__ __launch_bounds__(1024) void k_scan(const int* __restrict__ cnt, int* __restrict__ row_ptr,
                                               int* __restrict__ cursor, float* __restrict__ inv_deg){
  __shared__ int part[1024];
  int t = threadIdx.x;
  int base = t*10;
  int local[10]; int s = 0;
  for (int i=0;i<10;i++){
    int idx = base+i;
    int v = (idx < N_NODES) ? cnt[idx] : 0;
    local[i] = s; s += v;
  }
  part[t] = s;
  __syncthreads();
  for (int off=1; off<1024; off<<=1){
    int v = (t>=off) ? part[t-off] : 0;
    __syncthreads();
    part[t] += v;
    __syncthreads();
  }
  int prev = (t==0) ? 0 : part[t-1];
  for (int i=0;i<10;i++){
    int idx = base+i;
    if (idx < N_NODES){
      int rp = prev + local[i];
      row_ptr[idx] = rp; cursor[idx] = rp;
      int c = cnt[idx];
      inv_deg[idx] = 1.0f / (float)(c > 0 ? c : 1);
    }
  }
  if (t==1023) row_ptr[N_NODES] = part[1023];
}

__global__ void k_fill(const int* __restrict__ src, const int* __restrict__ dst,
                       int* __restrict__ cursor, int* __restrict__ csr_src){
  int e = blockIdx.x*256 + threadIdx.x;
  if (e < N_EDGES){
    int pos = atomicAdd(&cursor[dst[e]], 1);
    csr_src[pos] = src[e];
  }
}

// ---------------- prep: wcat (fp32->bf16 concat) + copy_x + zero scratch ----------------
#define NZERO 14656   // cnt(10048) + stats(4096) + bias0(512)
__global__ __launch_bounds__(256) void k_prep(const float* __restrict__ wpr, const float* __restrict__ wpo,
                                              const float* __restrict__ wrel, const float* __restrict__ wroot,
                                              const float* __restrict__ wfr, const float* __restrict__ wfo,
                                              const float* __restrict__ x,
                                              u16* __restrict__ Wcat, u16* __restrict__ Wfin,
                                              u16* __restrict__ A, u32* __restrict__ zreg){
  int b = blockIdx.x, t = threadIdx.x;
  if (b < 4096){
    int i = b*256 + t;
    int lyr = i >> 18;
    int r   = i & 262143;
    int o = r >> 9, k = r & 511;
    const float* R = (lyr==0) ? wpr : wrel  + (size_t)(lyr-1)*262144;
    const float* O = (lyr==0) ? wpo : wroot + (size_t)(lyr-1)*262144;
    Wcat[(size_t)lyr*524288 + (size_t)o*KDIM + k]        = f2bf(R[r]);
    Wcat[(size_t)lyr*524288 + (size_t)o*KDIM + HDIM + k] = f2bf(O[r]);
    if (i < 10*512){
      int oo = i >> 9, kk = i & 511;
      Wfin[oo*KDIM + kk]        = f2bf(wfr[i]);
      Wfin[oo*KDIM + HDIM + kk] = f2bf(wfo[i]);
    }
  } else if (b < 9096){
    int c = (b-4096)*256 + t;
    int n = c >> 7, o = (c & 127)*4;
    float4 v = *(const float4*)(x + (size_t)n*HDIM + o);
    ushort4 bb;
    bb.x = f2bf(v.x); bb.y = f2bf(v.y); bb.z = f2bf(v.z); bb.w = f2bf(v.w);
    *(ushort4*)(A + (size_t)n*KDIM + HDIM + o) = bb;
  } else {
    int i = (b-9096)*256 + t;
    if (i < NZERO) zreg[i] = 0u;
  }
}

// ================= agg core: one WAVE per node, no LDS, no barriers =================
// lane l accumulates cols l*8 .. l*8+7 (fp32) of mean_{s in nbrs(n)} Abuf[s][512:1024]
__device__ __forceinline__ void agg_wave_core(int n, const u16* __restrict__ Abuf,
                                              const int* __restrict__ row_ptr, const int* __restrict__ cnt,
                                              const int* __restrict__ csr, const float* __restrict__ inv_deg,
                                              float* __restrict__ a){
  int l = threadIdx.x & 63;
  int start = row_ptr[n], num = cnt[n];
  #pragma unroll
  for (int i=0;i<8;i++) a[i]=0.f;
  int j = 0;
  while (j + 1 < num){
    int s0 = csr[start + j];
    int s1 = csr[start + j + 1];
    uint4 v0 = *(const uint4*)(Abuf + (size_t)s0*KDIM + HDIM + l*8);
    uint4 v1 = *(const uint4*)(Abuf + (size_t)s1*KDIM + HDIM + l*8);
    a[0]+=bflo(v0.x); a[1]+=bfhi(v0.x); a[2]+=bflo(v0.y); a[3]+=bfhi(v0.y);
    a[4]+=bflo(v0.z); a[5]+=bfhi(v0.z); a[6]+=bflo(v0.w); a[7]+=bfhi(v0.w);
    a[0]+=bflo(v1.x); a[1]+=bfhi(v1.x); a[2]+=bflo(v1.y); a[3]+=bfhi(v1.y);
    a[4]+=bflo(v1.z); a[5]+=bfhi(v1.z); a[6]+=bflo(v1.w); a[7]+=bfhi(v1.w);
    j += 2;
  }
  if (j < num){
    int s = csr[start + j];
    uint4 v = *(const uint4*)(Abuf + (size_t)s*KDIM + HDIM + l*8);
    a[0]+=bflo(v.x); a[1]+=bfhi(v.x); a[2]+=bflo(v.y); a[3]+=bfhi(v.y);
    a[4]+=bflo(v.z); a[5]+=bfhi(v.z); a[6]+=bflo(v.w); a[7]+=bfhi(v.w);
  }
  float id = inv_deg[n];
  #pragma unroll
  for (int i=0;i<8;i++) a[i] *= id;
}

__device__ __forceinline__ void agg_write(int n, const float* __restrict__ a, u16* __restrict__ Aleft){
  int l = threadIdx.x & 63;
  u16 ob[8];
  #pragma unroll
  for (int i=0;i<8;i++) ob[i] = f2bf(a[i]);
  *(uint4*)(Aleft + (size_t)n*KDIM + l*8) = *(uint4*)ob;
}

// wscale row with fused BN finalize (whole block per row)
__device__ __forceinline__ void wscale_row(int o, const u16* __restrict__ Wsrc, const float* __restrict__ stats,
                                           const float* __restrict__ gamma, const float* __restrict__ beta,
                                           int layer, u16* __restrict__ Wdst, float* __restrict__ biasOut){
  __shared__ float wred[4];
  int t = threadIdx.x, l = t & 63, w = t >> 6;
  int k = t*4;
  int fk = k & 511;
  float a[4], b[4];
  #pragma unroll
  for (int i=0;i<4;i++){
    int f = fk + i;
    float mu  = stats[f] * (1.f/N_NODES);
    float var = stats[512+f] * (1.f/N_NODES) - mu*mu;
    float rs  = rsqrtf(var + 1e-5f);
    float g = gamma[layer*512+f];
    a[i] = g*rs;
    b[i] = beta[layer*512+f] - mu*a[i];
  }
  const u16* row = Wsrc + (size_t)o*KDIM;
  uint2 v = *(const uint2*)(row + k);
  float f0 = bflo(v.x), f1 = bfhi(v.x), f2 = bflo(v.y), f3 = bfhi(v.y);
  u16 od[4];
  od[0]=f2bf(f0*a[0]); od[1]=f2bf(f1*a[1]); od[2]=f2bf(f2*a[2]); od[3]=f2bf(f3*a[3]);
  *(ushort4*)(Wdst + (size_t)o*KDIM + k) = *(ushort4*)od;
  float bsum = f0*b[0] + f1*b[1] + f2*b[2] + f3*b[3];
  #pragma unroll
  for (int off=32; off; off>>=1) bsum += __shfl_down(bsum, off);
  if (l==0) wred[w] = bsum;
  __syncthreads();
  if (t==0) biasOut[o] = wred[0]+wred[1]+wred[2]+wred[3];
}

// ---------------- standalone agg (first aggregation) ----------------
__global__ __launch_bounds__(256) void k_agg(const u16* __restrict__ Abuf,
                                             const int* __restrict__ row_ptr, const int* __restrict__ cnt,
                                             const int* __restrict__ csr, const float* __restrict__ inv_deg,
                                             u16* __restrict__ Aleft){
  int n = blockIdx.x*4 + (threadIdx.x >> 6);
  float a[8];
  agg_wave_core(n, Abuf, row_ptr, cnt, csr, inv_deg, a);
  agg_write(n, a, Aleft);
}

// ---------------- fused wscale(blocks<512) + agg ----------------
__global__ __launch_bounds__(256) void k_aggws(const u16* __restrict__ Abuf,
                                               const int* __restrict__ row_ptr, const int* __restrict__ cnt,
                                               const int* __restrict__ csr, const float* __restrict__ inv_deg,
                                               u16* __restrict__ Aleft,
                                               const u16* __restrict__ Wsrc, const float* __restrict__ stats,
                                               const float* __restrict__ gamma, const float* __restrict__ beta,
                                               int layer, u16* __restrict__ Wdst, float* __restrict__ biasOut){
  if (blockIdx.x < 512)
    wscale_row(blockIdx.x, Wsrc, stats, gamma, beta, layer, Wdst, biasOut);
  int n = blockIdx.x*4 + (threadIdx.x >> 6);
  float a[8];
  agg_wave_core(n, Abuf, row_ptr, cnt, csr, inv_deg, a);
  agg_write(n, a, Aleft);
}

// ---------------- standalone wscale (last layer, 10 rows) ----------------
__global__ __launch_bounds__(256) void k_wscale(const u16* __restrict__ Wsrc, const float* __restrict__ stats,
                                                const float* __restrict__ gamma, const float* __restrict__ beta,
                                                int layer, u16* __restrict__ Wdst, float* __restrict__ biasOut){
  wscale_row(blockIdx.x, Wsrc, stats, gamma, beta, layer, Wdst, biasOut);
}

// ---------------- fused last agg + final conv (C=10) + log_softmax ----------------
__global__ __launch_bounds__(256) void k_aggfinal(const u16* __restrict__ A,
                                                  const int* __restrict__ row_ptr, const int* __restrict__ cnt,
                                                  const int* __restrict__ csr, const float* __restrict__ inv_deg,
                                                  const u16* __restrict__ Wf, const float* __restrict__ biasF,
                                                  float* __restrict__ out){
  int l = threadIdx.x & 63;
  int n = blockIdx.x*4 + (threadIdx.x >> 6);
  float a[8];
  agg_wave_core(n, A, row_ptr, cnt, csr, inv_deg, a);
  uint4 vh = *(const uint4*)(A + (size_t)n*KDIM + HDIM + l*8);
  float h0=bflo(vh.x),h1=bfhi(vh.x),h2=bflo(vh.y),h3=bfhi(vh.y);
  float h4=bflo(vh.z),h5=bfhi(vh.z),h6=bflo(vh.w),h7=bfhi(vh.w);
  float acc[10];
  #pragma unroll
  for (int c=0;c<10;c++){
    const u16* wrow = Wf + (size_t)c*KDIM;
    uint4 wl = *(const uint4*)(wrow + l*8);
    uint4 wr = *(const uint4*)(wrow + HDIM + l*8);
    acc[c] = a[0]*bflo(wl.x)+a[1]*bfhi(wl.x)+a[2]*bflo(wl.y)+a[3]*bfhi(wl.y)
           + a[4]*bflo(wl.z)+a[5]*bfhi(wl.z)+a[6]*bflo(wl.w)+a[7]*bfhi(wl.w)
           + h0*bflo(wr.x)+h1*bfhi(wr.x)+h2*bflo(wr.y)+h3*bfhi(wr.y)
           + h4*bflo(wr.z)+h5*bfhi(wr.z)+h6*bflo(wr.w)+h7*bfhi(wr.w);
  }
  #pragma unroll
  for (int c=0;c<10;c++)
    #pragma unroll
    for (int off=32; off; off>>=1)
      acc[c] += __shfl_down(acc[c], off);
  if (l == 0){
    #pragma unroll
    for (int c=0;c<10;c++) acc[c] += biasF[c];
    float m = acc[0];
    #pragma unroll
    for (int c=1;c<10;c++) m = fmaxf(m, acc[c]);
    float s = 0.f;
    #pragma unroll
    for (int c=0;c<10;c++) s += expf(acc[c]-m);
    float lse = m + logf(s);
    #pragma unroll
    for (int c=0;c<10;c++) out[n*10+c] = acc[c]-lse;
  }
}

// ---------------- GEMM 64x128 tile, K=1024, fused bias+relu+bf16 store+BN stats ----------------
__global__ __launch_bounds__(256) void k_gemm(const u16* __restrict__ A, const u16* __restrict__ W,
                                              const float* __restrict__ bias,
                                              u16* __restrict__ Hout, float* __restrict__ stats){
  __shared__ __align__(16) u16 As[64*32];
  __shared__ __align__(16) u16 Bs[128*32];
  __shared__ float red_s[2][128];
  __shared__ float red_q[2][128];
  const int id = blockIdx.x;
  const int t  = threadIdx.x;
  const int l  = t & 63;
  const int wv = t >> 6;
  const int wm = wv >> 1, wn = wv & 1;
  const int m0 = (id >> 2) * 64;
  const int n0 = (id & 3) * 128;

  const int c1 = t + 256;
  const size_t gA  = (size_t)(m0 + (t>>2))*KDIM + ((t&3)*8);
  const size_t gB0 = (size_t)(n0 + (t>>2))*KDIM + ((t&3)*8);
  const size_t gB1 = (size_t)(n0 + (c1>>2))*KDIM + ((c1&3)*8);

  f32x4 acc[2][4];
  #pragma unroll
  for (int i=0;i<2;i++)
    #pragma unroll
    for (int j=0;j<4;j++)
      acc[i][j] = f32x4{0.f,0.f,0.f,0.f};

  const int aoff = (wm*32 + (l&15))*32 + (l>>4)*8;
  const int boff = (wn*64 + (l&15))*32 + (l>>4)*8;

  for (int k0 = 0; k0 < KDIM; k0 += 32){
    __builtin_amdgcn_global_load_lds((const __attribute__((address_space(1))) void*)(A + gA + k0),
                                     (__attribute__((address_space(3))) void*)(As + t*8), 16, 0, 0);
    __builtin_amdgcn_global_load_lds((const __attribute__((address_space(1))) void*)(W + gB0 + k0),
                                     (__attribute__((address_space(3))) void*)(Bs + t*8), 16, 0, 0);
    __builtin_amdgcn_global_load_lds((const __attribute__((address_space(1))) void*)(W + gB1 + k0),
                                     (__attribute__((address_space(3))) void*)(Bs + c1*8), 16, 0, 0);
    __syncthreads();
    bf16x8 af[2], bfr[4];
    af[0] = *(const bf16x8*)(As + aoff);
    af[1] = *(const bf16x8*)(As + aoff + 16*32);
    #pragma unroll
    for (int nt=0; nt<4; nt++)
      bfr[nt] = *(const bf16x8*)(Bs + boff + nt*16*32);
    #pragma unroll
    for (int mt=0; mt<2; mt++)
      #pragma unroll
      for (int nt=0; nt<4; nt++)
        acc[mt][nt] = __builtin_amdgcn_mfma_f32_16x16x32_bf16(af[mt], bfr[nt], acc[mt][nt], 0, 0, 0);
    __syncthreads();
  }

  float bi[4], sc[4], qc[4];
  #pragma unroll
  for (int nt=0; nt<4; nt++){
    bi[nt] = bias[n0 + wn*64 + nt*16 + (l & 15)];
    sc[nt] = 0.f; qc[nt] = 0.f;
  }
  #pragma unroll
  for (int nt=0; nt<4; nt++){
    const int col = n0 + wn*64 + nt*16 + (l & 15);
    #pragma unroll
    for (int mt=0; mt<2; mt++){
      #pragma unroll
      for (int r=0; r<4; r++){
        const int row = m0 + wm*32 + mt*16 + (l>>4)*4 + r;
        if (row < N_NODES){
          float v = acc[mt][nt][r] + bi[nt];
          v = v > 0.f ? v : 0.f;
          sc[nt] += v; qc[nt] += v*v;
          Hout[(size_t)row*KDIM + HDIM + col] = f2bf(v);
        }
      }
    }
  }
  #pragma unroll
  for (int nt=0; nt<4; nt++){
    float s = sc[nt], q = qc[nt];
    s += __shfl_xor(s, 16); s += __shfl_xor(s, 32);
    q += __shfl_xor(q, 16); q += __shfl_xor(q, 32);
    if (l < 16){
      red_s[wm][wn*64 + nt*16 + l] = s;
      red_q[wm][wn*64 + nt*16 + l] = q;
    }
  }
  __syncthreads();
  if (t < 128){
    atomicAdd(&stats[n0 + t],       red_s[0][t] + red_s[1][t]);
    atomicAdd(&stats[512 + n0 + t], red_q[0][t] + red_q[1][t]);
  }
}

extern "C" void kernel_launch(void* const* d_in, const int* in_sizes, int n_in,
                              void* d_out, int out_size, void* d_ws, size_t ws_size,
                              hipStream_t stream){
  (void)in_sizes; (void)n_in; (void)out_size; (void)ws_size;
  const float* x     = (const float*)d_in[0];
  const int*   eidx  = (const int*)d_in[1];
  const float* wpr   = (const float*)d_in[2];
  const float* wpo   = (const float*)d_in[3];
  const float* wrel  = (const float*)d_in[4];
  const float* wroot = (const float*)d_in[5];
  const float* gamma = (const float*)d_in[6];
  const float* beta  = (const float*)d_in[7];
  const float* wfr   = (const float*)d_in[8];
  const float* wfo   = (const float*)d_in[9];
  const int* src  = eidx;
  const int* dstv = eidx + N_EDGES;

  char* p = (char*)d_ws;
  auto carve = [&](size_t b){ char* q = p; p += (b + 255) & ~(size_t)255; return q; };
  u16*  A0      = (u16*)carve((size_t)NPAD*KDIM*2);
  u16*  A1      = (u16*)carve((size_t)NPAD*KDIM*2);
  u16*  Wcat    = (u16*)carve((size_t)4*HDIM*KDIM*2);
  u16*  Wfin    = (u16*)carve((size_t)10*KDIM*2);
  u16*  Wsc     = (u16*)carve((size_t)HDIM*KDIM*2);
  u16*  WfinSc  = (u16*)carve((size_t)10*KDIM*2);
  int*   zreg   = (int*)carve((size_t)NZERO*4);
  int*   cnt    = zreg;
  float* stats  = (float*)(zreg + 10048);
  float* bias0  = (float*)(zreg + 10048 + 4096);
  int*  row_ptr = (int*)carve((N_NODES+1)*4);
  int*  cursor  = (int*)carve(N_NODES*4);
  int*  csr     = (int*)carve(N_EDGES*4);
  float* inv_deg= (float*)carve(N_NODES*4);
  float* biasN  = (float*)carve(512*4);
  float* biasF  = (float*)carve(512*4);
  float* outp   = (float*)d_out;

  k_prep<<<9154, 256, 0, stream>>>(wpr, wpo, wrel, wroot, wfr, wfo, x, Wcat, Wfin, A0, (u32*)zreg);
  k_hist<<<(N_EDGES+255)/256, 256, 0, stream>>>(dstv, cnt);
  k_scan<<<1, 1024, 0, stream>>>(cnt, row_ptr, cursor, inv_deg);
  k_fill<<<(N_EDGES+255)/256, 256, 0, stream>>>(src, dstv, cursor, csr);
  k_agg<<<2500, 256, 0, stream>>>(A0, row_ptr, cnt, csr, inv_deg, A0);

  u16* Ain = A0; u16* Aout = A1;
  for (int lyr=0; lyr<4; lyr++){
    const u16* Wthis = (lyr==0) ? Wcat : Wsc;
    const float* bthis = (lyr==0) ? bias0 : biasN;
    k_gemm<<<NTILES, 256, 0, stream>>>(Ain, Wthis, bthis, Aout, stats + lyr*1024);
    if (lyr < 3){
      k_aggws<<<2500, 256, 0, stream>>>(Aout, row_ptr, cnt, csr, inv_deg, Aout,
                                        Wcat + (size_t)(lyr+1)*HDIM*KDIM, stats + lyr*1024,
                                        gamma, beta, lyr, Wsc, biasN);
    } else {
      k_wscale<<<10, 256, 0, stream>>>(Wfin, stats + lyr*1024, gamma, beta, lyr, WfinSc, biasF);
      k_aggfinal<<<2500, 256, 0, stream>>>(Aout, row_ptr, cnt, csr, inv_deg, WfinSc, biasF, outp);
    }
    u16* tmp = Ain; Ain = Aout; Aout = tmp;
  }
}

// Round 9
// 356.822 us; speedup vs baseline: 2.7782x; 1.0358x over previous
//
#include <hip/hip_runtime.h>
#include <hip/hip_bf16.h>

typedef unsigned short u16;
typedef unsigned int   u32;

#define N_NODES 10000
#define N_EDGES 160000
#define HDIM    512
#define KDIM    1024
#define NPAD    10112   // 79 * 128
#define NTILES  632     // 158 m-tiles(64 rows) x 4 n-panels(128 cols)

typedef __attribute__((ext_vector_type(8))) __bf16 bf16x8;
typedef __attribute__((ext_vector_type(4))) float  f32x4;

__device__ __forceinline__ float bflo(u32 v){ return __builtin_bit_cast(float, v << 16); }
__device__ __forceinline__ float bfhi(u32 v){ return __builtin_bit_cast(float, v & 0xffff0000u); }
__device__ __forceinline__ u16   f2bf(float f){ __hip_bfloat16 h = __float2bfloat16(f); return __builtin_bit_cast(u16, h); }

// ---------------- CSR build ----------------
__global__ void k_hist(const int* __restrict__ dst, int* __restrict__ cnt){
  int e = blockIdx.x*256 + threadIdx.x;
  if (e < N_EDGES) atomicAdd(&cnt[dst[e]], 1);
}

__global__ __launch_bounds__(1024) void k_scan(const int* __restrict__ cnt, int* __restrict__ row_ptr,
                                               int* __restrict__ cursor, float* __restrict__ inv_deg){
  __shared__ int part[1024];
  int t = threadIdx.x;
  int base = t*10;
  int local[10]; int s = 0;
  for (int i=0;i<10;i++){
    int idx = base+i;
    int v = (idx < N_NODES) ? cnt[idx] : 0;
    local[i] = s; s += v;
  }
  part[t] = s;
  __syncthreads();
  for (int off=1; off<1024; off<<=1){
    int v = (t>=off) ? part[t-off] : 0;
    __syncthreads();
    part[t] += v;
    __syncthreads();
  }
  int prev = (t==0) ? 0 : part[t-1];
  for (int i=0;i<10;i++){
    int idx = base+i;
    if (idx < N_NODES){
      int rp = prev + local[i];
      row_ptr[idx] = rp; cursor[idx] = rp;
      int c = cnt[idx];
      inv_deg[idx] = 1.0f / (float)(c > 0 ? c : 1);
    }
  }
  if (t==1023) row_ptr[N_NODES] = part[1023];
}

__global__ void k_fill(const int* __restrict__ src, const int* __restrict__ dst,
                       int* __restrict__ cursor, int* __restrict__ csr_src){
  int e = blockIdx.x*256 + threadIdx.x;
  if (e < N_EDGES){
    int pos = atomicAdd(&cursor[dst[e]], 1);
    csr_src[pos] = src[e];
  }
}

// ---------------- prep: wcat (fp32->bf16 concat) + copy_x + zero scratch ----------------
#define NZERO 14656   // cnt(10048) + stats(4096) + bias0(512)
__global__ __launch_bounds__(256) void k_prep(const float* __restrict__ wpr, const float* __restrict__ wpo,
                                              const float* __restrict__ wrel, const float* __restrict__ wroot,
                                              const float* __restrict__ wfr, const float* __restrict__ wfo,
                                              const float* __restrict__ x,
                                              u16* __restrict__ Wcat, u16* __restrict__ Wfin,
                                              u16* __restrict__ A, u32* __restrict__ zreg){
  int b = blockIdx.x, t = threadIdx.x;
  if (b < 4096){
    int i = b*256 + t;
    int lyr = i >> 18;
    int r   = i & 262143;
    int o = r >> 9, k = r & 511;
    const float* R = (lyr==0) ? wpr : wrel  + (size_t)(lyr-1)*262144;
    const float* O = (lyr==0) ? wpo : wroot + (size_t)(lyr-1)*262144;
    Wcat[(size_t)lyr*524288 + (size_t)o*KDIM + k]        = f2bf(R[r]);
    Wcat[(size_t)lyr*524288 + (size_t)o*KDIM + HDIM + k] = f2bf(O[r]);
    if (i < 10*512){
      int oo = i >> 9, kk = i & 511;
      Wfin[oo*KDIM + kk]        = f2bf(wfr[i]);
      Wfin[oo*KDIM + HDIM + kk] = f2bf(wfo[i]);
    }
  } else if (b < 9096){
    int c = (b-4096)*256 + t;
    int n = c >> 7, o = (c & 127)*4;
    float4 v = *(const float4*)(x + (size_t)n*HDIM + o);
    ushort4 bb;
    bb.x = f2bf(v.x); bb.y = f2bf(v.y); bb.z = f2bf(v.z); bb.w = f2bf(v.w);
    *(ushort4*)(A + (size_t)n*KDIM + HDIM + o) = bb;
  } else {
    int i = (b-9096)*256 + t;
    if (i < NZERO) zreg[i] = 0u;
  }
}

// ================= agg core: 4 waves per node, COLUMN-partitioned =================
// wave w owns cols [w*128, w*128+128); lane l holds col pair (w*128+2l, +1) in fp32 (a0,a1).
// No LDS, no barriers. 4 rows in flight, csr indices prefetched one iteration ahead.
__device__ __forceinline__ void agg_seg(int n, const u16* __restrict__ Abuf,
                                        const int* __restrict__ row_ptr, const int* __restrict__ cnt,
                                        const int* __restrict__ csr, const float* __restrict__ inv_deg,
                                        float& a0, float& a1){
  int t = threadIdx.x, l = t & 63, w = t >> 6;
  int start = row_ptr[n], num = cnt[n];
  const u16* base = Abuf + HDIM + (w*128 + 2*l);
  a0 = 0.f; a1 = 0.f;
  int s0=0,s1=0,s2=0,s3=0;
  if (0 < num) s0 = csr[start+0];
  if (1 < num) s1 = csr[start+1];
  if (2 < num) s2 = csr[start+2];
  if (3 < num) s3 = csr[start+3];
  int j = 0;
  while (j + 4 <= num){
    int t0=s0, t1=s1, t2=s2, t3=s3;
    int jn = j + 4;
    if (jn+0 < num) s0 = csr[start+jn+0];
    if (jn+1 < num) s1 = csr[start+jn+1];
    if (jn+2 < num) s2 = csr[start+jn+2];
    if (jn+3 < num) s3 = csr[start+jn+3];
    u32 v0 = *(const u32*)(base + (size_t)t0*KDIM);
    u32 v1 = *(const u32*)(base + (size_t)t1*KDIM);
    u32 v2 = *(const u32*)(base + (size_t)t2*KDIM);
    u32 v3 = *(const u32*)(base + (size_t)t3*KDIM);
    a0 += bflo(v0)+bflo(v1)+bflo(v2)+bflo(v3);
    a1 += bfhi(v0)+bfhi(v1)+bfhi(v2)+bfhi(v3);
    j = jn;
  }
  if (j+0 < num){ u32 v=*(const u32*)(base+(size_t)s0*KDIM); a0+=bflo(v); a1+=bfhi(v); }
  if (j+1 < num){ u32 v=*(const u32*)(base+(size_t)s1*KDIM); a0+=bflo(v); a1+=bfhi(v); }
  if (j+2 < num){ u32 v=*(const u32*)(base+(size_t)s2*KDIM); a0+=bflo(v); a1+=bfhi(v); }
  float id = inv_deg[n];
  a0 *= id; a1 *= id;
}

__device__ __forceinline__ void agg_seg_write(int n, float a0, float a1, u16* __restrict__ Aleft){
  int t = threadIdx.x, l = t & 63, w = t >> 6;
  u32 o = ((u32)f2bf(a1) << 16) | (u32)f2bf(a0);
  *(u32*)(Aleft + (size_t)n*KDIM + w*128 + 2*l) = o;
}

// wscale row with fused BN finalize (whole block per row)
__device__ __forceinline__ void wscale_row(int o, const u16* __restrict__ Wsrc, const float* __restrict__ stats,
                                           const float* __restrict__ gamma, const float* __restrict__ beta,
                                           int layer, u16* __restrict__ Wdst, float* __restrict__ biasOut){
  __shared__ float wred[4];
  int t = threadIdx.x, l = t & 63, w = t >> 6;
  int k = t*4;
  int fk = k & 511;
  float a[4], b[4];
  #pragma unroll
  for (int i=0;i<4;i++){
    int f = fk + i;
    float mu  = stats[f] * (1.f/N_NODES);
    float var = stats[512+f] * (1.f/N_NODES) - mu*mu;
    float rs  = rsqrtf(var + 1e-5f);
    float g = gamma[layer*512+f];
    a[i] = g*rs;
    b[i] = beta[layer*512+f] - mu*a[i];
  }
  const u16* row = Wsrc + (size_t)o*KDIM;
  uint2 v = *(const uint2*)(row + k);
  float f0 = bflo(v.x), f1 = bfhi(v.x), f2 = bflo(v.y), f3 = bfhi(v.y);
  u16 od[4];
  od[0]=f2bf(f0*a[0]); od[1]=f2bf(f1*a[1]); od[2]=f2bf(f2*a[2]); od[3]=f2bf(f3*a[3]);
  *(ushort4*)(Wdst + (size_t)o*KDIM + k) = *(ushort4*)od;
  float bsum = f0*b[0] + f1*b[1] + f2*b[2] + f3*b[3];
  #pragma unroll
  for (int off=32; off; off>>=1) bsum += __shfl_down(bsum, off);
  if (l==0) wred[w] = bsum;
  __syncthreads();
  if (t==0) biasOut[o] = wred[0]+wred[1]+wred[2]+wred[3];
}

// ---------------- standalone agg (first aggregation): one node per block ----------------
__global__ __launch_bounds__(256) void k_agg(const u16* __restrict__ Abuf,
                                             const int* __restrict__ row_ptr, const int* __restrict__ cnt,
                                             const int* __restrict__ csr, const float* __restrict__ inv_deg,
                                             u16* __restrict__ Aleft){
  float a0, a1;
  agg_seg(blockIdx.x, Abuf, row_ptr, cnt, csr, inv_deg, a0, a1);
  agg_seg_write(blockIdx.x, a0, a1, Aleft);
}

// ---------------- fused wscale(blocks<512) + agg ----------------
__global__ __launch_bounds__(256) void k_aggws(const u16* __restrict__ Abuf,
                                               const int* __restrict__ row_ptr, const int* __restrict__ cnt,
                                               const int* __restrict__ csr, const float* __restrict__ inv_deg,
                                               u16* __restrict__ Aleft,
                                               const u16* __restrict__ Wsrc, const float* __restrict__ stats,
                                               const float* __restrict__ gamma, const float* __restrict__ beta,
                                               int layer, u16* __restrict__ Wdst, float* __restrict__ biasOut){
  if (blockIdx.x < 512)
    wscale_row(blockIdx.x, Wsrc, stats, gamma, beta, layer, Wdst, biasOut);
  float a0, a1;
  agg_seg(blockIdx.x, Abuf, row_ptr, cnt, csr, inv_deg, a0, a1);
  agg_seg_write(blockIdx.x, a0, a1, Aleft);
}

// ---------------- standalone wscale (last layer, 10 rows) ----------------
__global__ __launch_bounds__(256) void k_wscale(const u16* __restrict__ Wsrc, const float* __restrict__ stats,
                                                const float* __restrict__ gamma, const float* __restrict__ beta,
                                                int layer, u16* __restrict__ Wdst, float* __restrict__ biasOut){
  wscale_row(blockIdx.x, Wsrc, stats, gamma, beta, layer, Wdst, biasOut);
}

// ---------------- fused last agg + final conv (C=10) + log_softmax: one node per block ----------------
__global__ __launch_bounds__(256) void k_aggfinal(const u16* __restrict__ A,
                                                  const int* __restrict__ row_ptr, const int* __restrict__ cnt,
                                                  const int* __restrict__ csr, const float* __restrict__ inv_deg,
                                                  const u16* __restrict__ Wf, const float* __restrict__ biasF,
                                                  float* __restrict__ out){
  __shared__ float red[4][10];
  int n = blockIdx.x;
  int t = threadIdx.x, l = t & 63, w = t >> 6;
  float a0, a1;
  agg_seg(n, A, row_ptr, cnt, csr, inv_deg, a0, a1);
  // h segment (root features, right half of A)
  u32 vh = *(const u32*)(A + (size_t)n*KDIM + HDIM + w*128 + 2*l);
  float h0 = bflo(vh), h1 = bfhi(vh);
  float acc[10];
  #pragma unroll
  for (int c=0;c<10;c++){
    const u16* wrow = Wf + (size_t)c*KDIM + w*128 + 2*l;
    u32 wl = *(const u32*)wrow;          // agg-weight cols
    u32 wr = *(const u32*)(wrow + HDIM); // root-weight cols
    acc[c] = a0*bflo(wl) + a1*bfhi(wl) + h0*bflo(wr) + h1*bfhi(wr);
  }
  #pragma unroll
  for (int c=0;c<10;c++)
    #pragma unroll
    for (int off=32; off; off>>=1)
      acc[c] += __shfl_down(acc[c], off);
  if (l == 0){
    #pragma unroll
    for (int c=0;c<10;c++) red[w][c] = acc[c];
  }
  __syncthreads();
  if (t == 0){
    float fin[10];
    #pragma unroll
    for (int c=0;c<10;c++)
      fin[c] = red[0][c]+red[1][c]+red[2][c]+red[3][c] + biasF[c];
    float m = fin[0];
    #pragma unroll
    for (int c=1;c<10;c++) m = fmaxf(m, fin[c]);
    float s = 0.f;
    #pragma unroll
    for (int c=0;c<10;c++) s += expf(fin[c]-m);
    float lse = m + logf(s);
    #pragma unroll
    for (int c=0;c<10;c++) out[n*10+c] = fin[c]-lse;
  }
}

// ---------------- GEMM 64x128 tile, K=1024, fused bias+relu+bf16 store+BN stats ----------------
__global__ __launch_bounds__(256) void k_gemm(const u16* __restrict__ A, const u16* __restrict__ W,
                                              const float* __restrict__ bias,
                                              u16* __restrict__ Hout, float* __restrict__ stats){
  __shared__ __align__(16) u16 As[64*32];
  __shared__ __align__(16) u16 Bs[128*32];
  __shared__ float red_s[2][128];
  __shared__ float red_q[2][128];
  const int id = blockIdx.x;
  const int t  = threadIdx.x;
  const int l  = t & 63;
  const int wv = t >> 6;
  const int wm = wv >> 1, wn = wv & 1;
  const int m0 = (id >> 2) * 64;
  const int n0 = (id & 3) * 128;

  const int c1 = t + 256;
  const size_t gA  = (size_t)(m0 + (t>>2))*KDIM + ((t&3)*8);
  const size_t gB0 = (size_t)(n0 + (t>>2))*KDIM + ((t&3)*8);
  const size_t gB1 = (size_t)(n0 + (c1>>2))*KDIM + ((c1&3)*8);

  f32x4 acc[2][4];
  #pragma unroll
  for (int i=0;i<2;i++)
    #pragma unroll
    for (int j=0;j<4;j++)
      acc[i][j] = f32x4{0.f,0.f,0.f,0.f};

  const int aoff = (wm*32 + (l&15))*32 + (l>>4)*8;
  const int boff = (wn*64 + (l&15))*32 + (l>>4)*8;

  for (int k0 = 0; k0 < KDIM; k0 += 32){
    __builtin_amdgcn_global_load_lds((const __attribute__((address_space(1))) void*)(A + gA + k0),
                                     (__attribute__((address_space(3))) void*)(As + t*8), 16, 0, 0);
    __builtin_amdgcn_global_load_lds((const __attribute__((address_space(1))) void*)(W + gB0 + k0),
                                     (__attribute__((address_space(3))) void*)(Bs + t*8), 16, 0, 0);
    __builtin_amdgcn_global_load_lds((const __attribute__((address_space(1))) void*)(W + gB1 + k0),
                                     (__attribute__((address_space(3))) void*)(Bs + c1*8), 16, 0, 0);
    __syncthreads();
    bf16x8 af[2], bfr[4];
    af[0] = *(const bf16x8*)(As + aoff);
    af[1] = *(const bf16x8*)(As + aoff + 16*32);
    #pragma unroll
    for (int nt=0; nt<4; nt++)
      bfr[nt] = *(const bf16x8*)(Bs + boff + nt*16*32);
    #pragma unroll
    for (int mt=0; mt<2; mt++)
      #pragma unroll
      for (int nt=0; nt<4; nt++)
        acc[mt][nt] = __builtin_amdgcn_mfma_f32_16x16x32_bf16(af[mt], bfr[nt], acc[mt][nt], 0, 0, 0);
    __syncthreads();
  }

  float bi[4], sc[4], qc[4];
  #pragma unroll
  for (int nt=0; nt<4; nt++){
    bi[nt] = bias[n0 + wn*64 + nt*16 + (l & 15)];
    sc[nt] = 0.f; qc[nt] = 0.f;
  }
  #pragma unroll
  for (int nt=0; nt<4; nt++){
    const int col = n0 + wn*64 + nt*16 + (l & 15);
    #pragma unroll
    for (int mt=0; mt<2; mt++){
      #pragma unroll
      for (int r=0; r<4; r++){
        const int row = m0 + wm*32 + mt*16 + (l>>4)*4 + r;
        if (row < N_NODES){
          float v = acc[mt][nt][r] + bi[nt];
          v = v > 0.f ? v : 0.f;
          sc[nt] += v; qc[nt] += v*v;
          Hout[(size_t)row*KDIM + HDIM + col] = f2bf(v);
        }
      }
    }
  }
  #pragma unroll
  for (int nt=0; nt<4; nt++){
    float s = sc[nt], q = qc[nt];
    s += __shfl_xor(s, 16); s += __shfl_xor(s, 32);
    q += __shfl_xor(q, 16); q += __shfl_xor(q, 32);
    if (l < 16){
      red_s[wm][wn*64 + nt*16 + l] = s;
      red_q[wm][wn*64 + nt*16 + l] = q;
    }
  }
  __syncthreads();
  if (t < 128){
    atomicAdd(&stats[n0 + t],       red_s[0][t] + red_s[1][t]);
    atomicAdd(&stats[512 + n0 + t], red_q[0][t] + red_q[1][t]);
  }
}

extern "C" void kernel_launch(void* const* d_in, const int* in_sizes, int n_in,
                              void* d_out, int out_size, void* d_ws, size_t ws_size,
                              hipStream_t stream){
  (void)in_sizes; (void)n_in; (void)out_size; (void)ws_size;
  const float* x     = (const float*)d_in[0];
  const int*   eidx  = (const int*)d_in[1];
  const float* wpr   = (const float*)d_in[2];
  const float* wpo   = (const float*)d_in[3];
  const float* wrel  = (const float*)d_in[4];
  const float* wroot = (const float*)d_in[5];
  const float* gamma = (const float*)d_in[6];
  const float* beta  = (const float*)d_in[7];
  const float* wfr   = (const float*)d_in[8];
  const float* wfo   = (const float*)d_in[9];
  const int* src  = eidx;
  const int* dstv = eidx + N_EDGES;

  char* p = (char*)d_ws;
  auto carve = [&](size_t b){ char* q = p; p += (b + 255) & ~(size_t)255; return q; };
  u16*  A0      = (u16*)carve((size_t)NPAD*KDIM*2);
  u16*  A1      = (u16*)carve((size_t)NPAD*KDIM*2);
  u16*  Wcat    = (u16*)carve((size_t)4*HDIM*KDIM*2);
  u16*  Wfin    = (u16*)carve((size_t)10*KDIM*2);
  u16*  Wsc     = (u16*)carve((size_t)HDIM*KDIM*2);
  u16*  WfinSc  = (u16*)carve((size_t)10*KDIM*2);
  int*   zreg   = (int*)carve((size_t)NZERO*4);
  int*   cnt    = zreg;
  float* stats  = (float*)(zreg + 10048);
  float* bias0  = (float*)(zreg + 10048 + 4096);
  int*  row_ptr = (int*)carve((N_NODES+1)*4);
  int*  cursor  = (int*)carve(N_NODES*4);
  int*  csr     = (int*)carve(N_EDGES*4);
  float* inv_deg= (float*)carve(N_NODES*4);
  float* biasN  = (float*)carve(512*4);
  float* biasF  = (float*)carve(512*4);
  float* outp   = (float*)d_out;

  k_prep<<<9154, 256, 0, stream>>>(wpr, wpo, wrel, wroot, wfr, wfo, x, Wcat, Wfin, A0, (u32*)zreg);
  k_hist<<<(N_EDGES+255)/256, 256, 0, stream>>>(dstv, cnt);
  k_scan<<<1, 1024, 0, stream>>>(cnt, row_ptr, cursor, inv_deg);
  k_fill<<<(N_EDGES+255)/256, 256, 0, stream>>>(src, dstv, cursor, csr);
  k_agg<<<N_NODES, 256, 0, stream>>>(A0, row_ptr, cnt, csr, inv_deg, A0);

  u16* Ain = A0; u16* Aout = A1;
  for (int lyr=0; lyr<4; lyr++){
    const u16* Wthis = (lyr==0) ? Wcat : Wsc;
    const float* bthis = (lyr==0) ? bias0 : biasN;
    k_gemm<<<NTILES, 256, 0, stream>>>(Ain, Wthis, bthis, Aout, stats + lyr*1024);
    if (lyr < 3){
      k_aggws<<<N_NODES, 256, 0, stream>>>(Aout, row_ptr, cnt, csr, inv_deg, Aout,
                                           Wcat + (size_t)(lyr+1)*HDIM*KDIM, stats + lyr*1024,
                                           gamma, beta, lyr, Wsc, biasN);
    } else {
      k_wscale<<<10, 256, 0, stream>>>(Wfin, stats + lyr*1024, gamma, beta, lyr, WfinSc, biasF);
      k_aggfinal<<<N_NODES, 256, 0, stream>>>(Aout, row_ptr, cnt, csr, inv_deg, WfinSc, biasF, outp);
    }
    u16* tmp = Ain; Ain = Aout; Aout = tmp;
  }
}

// Round 10
// 353.819 us; speedup vs baseline: 2.8018x; 1.0085x over previous
//
#include <hip/hip_runtime.h>
#include <hip/hip_bf16.h>

typedef unsigned short u16;
typedef unsigned int   u32;

#define N_NODES 10000
#define N_EDGES 160000
#define HDIM    512
#define KDIM    1024
#define NPAD    10112   // 79 * 128
#define NTILES  632     // 158 m-tiles(64 rows) x 4 n-panels(128 cols)

typedef __attribute__((ext_vector_type(8))) __bf16 bf16x8;
typedef __attribute__((ext_vector_type(4))) float  f32x4;

__device__ __forceinline__ float bflo(u32 v){ return __builtin_bit_cast(float, v << 16); }
__device__ __forceinline__ float bfhi(u32 v){ return __builtin_bit_cast(float, v & 0xffff0000u); }
__device__ __forceinline__ u16   f2bf(float f){ __hip_bfloat16 h = __float2bfloat16(f); return __builtin_bit_cast(u16, h); }

// ---------------- CSR build ----------------
__global__ void k_hist(const int* __restrict__ dst, int* __restrict__ cnt){
  int e = blockIdx.x*256 + threadIdx.x;
  if (e < N_EDGES) atomicAdd(&cnt[dst[e]], 1);
}

__global__ __launch_bounds__(1024) void k_scan(const int* __restrict__ cnt, int* __restrict__ row_ptr,
                                               int* __restrict__ cursor, float* __restrict__ inv_deg){
  __shared__ int part[1024];
  int t = threadIdx.x;
  int base = t*10;
  int local[10]; int s = 0;
  for (int i=0;i<10;i++){
    int idx = base+i;
    int v = (idx < N_NODES) ? cnt[idx] : 0;
    local[i] = s; s += v;
  }
  part[t] = s;
  __syncthreads();
  for (int off=1; off<1024; off<<=1){
    int v = (t>=off) ? part[t-off] : 0;
    __syncthreads();
    part[t] += v;
    __syncthreads();
  }
  int prev = (t==0) ? 0 : part[t-1];
  for (int i=0;i<10;i++){
    int idx = base+i;
    if (idx < N_NODES){
      int rp = prev + local[i];
      row_ptr[idx] = rp; cursor[idx] = rp;
      int c = cnt[idx];
      inv_deg[idx] = 1.0f / (float)(c > 0 ? c : 1);
    }
  }
  if (t==1023) row_ptr[N_NODES] = part[1023];
}

__global__ void k_fill(const int* __restrict__ src, const int* __restrict__ dst,
                       int* __restrict__ cursor, int* __restrict__ csr_src){
  int e = blockIdx.x*256 + threadIdx.x;
  if (e < N_EDGES){
    int pos = atomicAdd(&cursor[dst[e]], 1);
    csr_src[pos] = src[e];
  }
}

// ---------------- prep: wcat (fp32->bf16 concat) + copy_x + zero scratch ----------------
#define NZERO 14656   // cnt(10048) + stats(4096) + bias0(512)
__global__ __launch_bounds__(256) void k_prep(const float* __restrict__ wpr, const float* __restrict__ wpo,
                                              const float* __restrict__ wrel, const float* __restrict__ wroot,
                                              const float* __restrict__ wfr, const float* __restrict__ wfo,
                                              const float* __restrict__ x,
                                              u16* __restrict__ Wcat, u16* __restrict__ Wfin,
                                              u16* __restrict__ A, u32* __restrict__ zreg){
  int b = blockIdx.x, t = threadIdx.x;
  if (b < 4096){
    int i = b*256 + t;
    int lyr = i >> 18;
    int r   = i & 262143;
    int o = r >> 9, k = r & 511;
    const float* R = (lyr==0) ? wpr : wrel  + (size_t)(lyr-1)*262144;
    const float* O = (lyr==0) ? wpo : wroot + (size_t)(lyr-1)*262144;
    Wcat[(size_t)lyr*524288 + (size_t)o*KDIM + k]        = f2bf(R[r]);
    Wcat[(size_t)lyr*524288 + (size_t)o*KDIM + HDIM + k] = f2bf(O[r]);
    if (i < 10*512){
      int oo = i >> 9, kk = i & 511;
      Wfin[oo*KDIM + kk]        = f2bf(wfr[i]);
      Wfin[oo*KDIM + HDIM + kk] = f2bf(wfo[i]);
    }
  } else if (b < 9096){
    int c = (b-4096)*256 + t;
    int n = c >> 7, o = (c & 127)*4;
    float4 v = *(const float4*)(x + (size_t)n*HDIM + o);
    ushort4 bb;
    bb.x = f2bf(v.x); bb.y = f2bf(v.y); bb.z = f2bf(v.z); bb.w = f2bf(v.w);
    *(ushort4*)(A + (size_t)n*KDIM + HDIM + o) = bb;
  } else {
    int i = (b-9096)*256 + t;
    if (i < NZERO) zreg[i] = 0u;
  }
}

// ================= agg core: 2 waves per node, 4 cols (8B)/lane, 8-deep pipeline =================
// wave w (0/1 within node) owns cols [w*256, w*256+256); lane l holds cols w*256+4l .. +3.
__device__ __forceinline__ void agg_seg4(int n, const u16* __restrict__ Abuf,
                                         const int* __restrict__ row_ptr, const int* __restrict__ cnt,
                                         const int* __restrict__ csr, const float* __restrict__ inv_deg,
                                         int w, int l, float* __restrict__ a){
  int start = row_ptr[n], num = cnt[n];
  const u16* base = Abuf + HDIM + w*256 + 4*l;
  a[0]=0.f; a[1]=0.f; a[2]=0.f; a[3]=0.f;
  int s[8];
  #pragma unroll
  for (int i=0;i<8;i++) s[i] = (i < num) ? csr[start+i] : 0;
  int j = 0;
  while (j + 8 <= num){
    int cur[8];
    #pragma unroll
    for (int i=0;i<8;i++) cur[i] = s[i];
    int jn = j + 8;
    #pragma unroll
    for (int i=0;i<8;i++) s[i] = (jn+i < num) ? csr[start+jn+i] : 0;
    #pragma unroll
    for (int i=0;i<8;i++){
      uint2 v = *(const uint2*)(base + (size_t)cur[i]*KDIM);
      a[0]+=bflo(v.x); a[1]+=bfhi(v.x); a[2]+=bflo(v.y); a[3]+=bfhi(v.y);
    }
    j = jn;
  }
  #pragma unroll
  for (int i=0;i<8;i++){
    if (j+i < num){
      uint2 v = *(const uint2*)(base + (size_t)s[i]*KDIM);
      a[0]+=bflo(v.x); a[1]+=bfhi(v.x); a[2]+=bflo(v.y); a[3]+=bfhi(v.y);
    }
  }
  float id = inv_deg[n];
  #pragma unroll
  for (int i=0;i<4;i++) a[i] *= id;
}

__device__ __forceinline__ void agg_write4(int n, int w, int l, const float* __restrict__ a,
                                           u16* __restrict__ Aleft){
  ushort4 ob;
  ob.x = f2bf(a[0]); ob.y = f2bf(a[1]); ob.z = f2bf(a[2]); ob.w = f2bf(a[3]);
  *(ushort4*)(Aleft + (size_t)n*KDIM + w*256 + 4*l) = ob;
}

// wscale row with fused BN finalize (whole block per row)
__device__ __forceinline__ void wscale_row(int o, const u16* __restrict__ Wsrc, const float* __restrict__ stats,
                                           const float* __restrict__ gamma, const float* __restrict__ beta,
                                           int layer, u16* __restrict__ Wdst, float* __restrict__ biasOut){
  __shared__ float wred[4];
  int t = threadIdx.x, l = t & 63, w = t >> 6;
  int k = t*4;
  int fk = k & 511;
  float a[4], b[4];
  #pragma unroll
  for (int i=0;i<4;i++){
    int f = fk + i;
    float mu  = stats[f] * (1.f/N_NODES);
    float var = stats[512+f] * (1.f/N_NODES) - mu*mu;
    float rs  = rsqrtf(var + 1e-5f);
    float g = gamma[layer*512+f];
    a[i] = g*rs;
    b[i] = beta[layer*512+f] - mu*a[i];
  }
  const u16* row = Wsrc + (size_t)o*KDIM;
  uint2 v = *(const uint2*)(row + k);
  float f0 = bflo(v.x), f1 = bfhi(v.x), f2 = bflo(v.y), f3 = bfhi(v.y);
  u16 od[4];
  od[0]=f2bf(f0*a[0]); od[1]=f2bf(f1*a[1]); od[2]=f2bf(f2*a[2]); od[3]=f2bf(f3*a[3]);
  *(ushort4*)(Wdst + (size_t)o*KDIM + k) = *(ushort4*)od;
  float bsum = f0*b[0] + f1*b[1] + f2*b[2] + f3*b[3];
  #pragma unroll
  for (int off=32; off; off>>=1) bsum += __shfl_down(bsum, off);
  if (l==0) wred[w] = bsum;
  __syncthreads();
  if (t==0) biasOut[o] = wred[0]+wred[1]+wred[2]+wred[3];
}

// ---------------- standalone agg (first aggregation): 2 nodes per block ----------------
__global__ __launch_bounds__(256) void k_agg(const u16* __restrict__ Abuf,
                                             const int* __restrict__ row_ptr, const int* __restrict__ cnt,
                                             const int* __restrict__ csr, const float* __restrict__ inv_deg,
                                             u16* __restrict__ Aleft){
  int t = threadIdx.x, nib = t >> 7, w = (t >> 6) & 1, l = t & 63;
  int n = blockIdx.x*2 + nib;
  float a[4];
  agg_seg4(n, Abuf, row_ptr, cnt, csr, inv_deg, w, l, a);
  agg_write4(n, w, l, a, Aleft);
}

// ---------------- fused wscale(blocks<512) + agg (2 nodes per block) ----------------
__global__ __launch_bounds__(256) void k_aggws(const u16* __restrict__ Abuf,
                                               const int* __restrict__ row_ptr, const int* __restrict__ cnt,
                                               const int* __restrict__ csr, const float* __restrict__ inv_deg,
                                               u16* __restrict__ Aleft,
                                               const u16* __restrict__ Wsrc, const float* __restrict__ stats,
                                               const float* __restrict__ gamma, const float* __restrict__ beta,
                                               int layer, u16* __restrict__ Wdst, float* __restrict__ biasOut){
  if (blockIdx.x < 512)
    wscale_row(blockIdx.x, Wsrc, stats, gamma, beta, layer, Wdst, biasOut);
  int t = threadIdx.x, nib = t >> 7, w = (t >> 6) & 1, l = t & 63;
  int n = blockIdx.x*2 + nib;
  float a[4];
  agg_seg4(n, Abuf, row_ptr, cnt, csr, inv_deg, w, l, a);
  agg_write4(n, w, l, a, Aleft);
}

// ---------------- fused last agg + inline BN-fold + final conv (C=10) + log_softmax ----------------
// 2 nodes per block, 2 waves per node. Lane covers 4 agg cols (k0..k0+3) and 4 root cols (+512).
__global__ __launch_bounds__(256) void k_aggfinal(const u16* __restrict__ A,
                                                  const int* __restrict__ row_ptr, const int* __restrict__ cnt,
                                                  const int* __restrict__ csr, const float* __restrict__ inv_deg,
                                                  const u16* __restrict__ Wfin, const float* __restrict__ stats,
                                                  const float* __restrict__ gamma, const float* __restrict__ beta,
                                                  float* __restrict__ out){
  __shared__ float red[2][2][10];
  int t = threadIdx.x, nib = t >> 7, w = (t >> 6) & 1, l = t & 63;
  int n = blockIdx.x*2 + nib;
  float a[4];
  agg_seg4(n, A, row_ptr, cnt, csr, inv_deg, w, l, a);
  int k0 = w*256 + 4*l;
  // inline BN finalize for my 4 feature columns (layer 3)
  float aa[4], bb[4];
  #pragma unroll
  for (int i=0;i<4;i++){
    int f = k0 + i;
    float mu  = stats[f] * (1.f/N_NODES);
    float var = stats[512+f] * (1.f/N_NODES) - mu*mu;
    float rs  = rsqrtf(var + 1e-5f);
    float g = gamma[3*512+f];
    aa[i] = g*rs;
    bb[i] = beta[3*512+f] - mu*aa[i];
  }
  uint2 vh = *(const uint2*)(A + (size_t)n*KDIM + HDIM + k0);
  float h[4] = { bflo(vh.x), bfhi(vh.x), bflo(vh.y), bfhi(vh.y) };
  float ga[4], gh[4];
  #pragma unroll
  for (int i=0;i<4;i++){ ga[i] = a[i]*aa[i] + bb[i]; gh[i] = h[i]*aa[i] + bb[i]; }
  float acc[10];
  #pragma unroll
  for (int c=0;c<10;c++){
    const u16* wr = Wfin + (size_t)c*KDIM + k0;
    uint2 w1 = *(const uint2*)wr;          // agg-side weights (raw)
    uint2 w2 = *(const uint2*)(wr + HDIM); // root-side weights (raw)
    acc[c] = ga[0]*bflo(w1.x)+ga[1]*bfhi(w1.x)+ga[2]*bflo(w1.y)+ga[3]*bfhi(w1.y)
           + gh[0]*bflo(w2.x)+gh[1]*bfhi(w2.x)+gh[2]*bflo(w2.y)+gh[3]*bfhi(w2.y);
  }
  #pragma unroll
  for (int c=0;c<10;c++)
    #pragma unroll
    for (int off=32; off; off>>=1)
      acc[c] += __shfl_down(acc[c], off);
  if (l == 0){
    #pragma unroll
    for (int c=0;c<10;c++) red[nib][w][c] = acc[c];
  }
  __syncthreads();
  if ((t & 127) == 0){
    float fin[10];
    #pragma unroll
    for (int c=0;c<10;c++) fin[c] = red[nib][0][c] + red[nib][1][c];
    float m = fin[0];
    #pragma unroll
    for (int c=1;c<10;c++) m = fmaxf(m, fin[c]);
    float s = 0.f;
    #pragma unroll
    for (int c=0;c<10;c++) s += expf(fin[c]-m);
    float lse = m + logf(s);
    #pragma unroll
    for (int c=0;c<10;c++) out[n*10+c] = fin[c]-lse;
  }
}

// ---------------- GEMM 64x128 tile, K=1024, fused bias+relu+bf16 store+BN stats ----------------
__global__ __launch_bounds__(256) void k_gemm(const u16* __restrict__ A, const u16* __restrict__ W,
                                              const float* __restrict__ bias,
                                              u16* __restrict__ Hout, float* __restrict__ stats){
  __shared__ __align__(16) u16 As[64*32];
  __shared__ __align__(16) u16 Bs[128*32];
  __shared__ float red_s[2][128];
  __shared__ float red_q[2][128];
  const int id = blockIdx.x;
  const int t  = threadIdx.x;
  const int l  = t & 63;
  const int wv = t >> 6;
  const int wm = wv >> 1, wn = wv & 1;
  const int m0 = (id >> 2) * 64;
  const int n0 = (id & 3) * 128;

  const int c1 = t + 256;
  const size_t gA  = (size_t)(m0 + (t>>2))*KDIM + ((t&3)*8);
  const size_t gB0 = (size_t)(n0 + (t>>2))*KDIM + ((t&3)*8);
  const size_t gB1 = (size_t)(n0 + (c1>>2))*KDIM + ((c1&3)*8);

  f32x4 acc[2][4];
  #pragma unroll
  for (int i=0;i<2;i++)
    #pragma unroll
    for (int j=0;j<4;j++)
      acc[i][j] = f32x4{0.f,0.f,0.f,0.f};

  const int aoff = (wm*32 + (l&15))*32 + (l>>4)*8;
  const int boff = (wn*64 + (l&15))*32 + (l>>4)*8;

  for (int k0 = 0; k0 < KDIM; k0 += 32){
    __builtin_amdgcn_global_load_lds((const __attribute__((address_space(1))) void*)(A + gA + k0),
                                     (__attribute__((address_space(3))) void*)(As + t*8), 16, 0, 0);
    __builtin_amdgcn_global_load_lds((const __attribute__((address_space(1))) void*)(W + gB0 + k0),
                                     (__attribute__((address_space(3))) void*)(Bs + t*8), 16, 0, 0);
    __builtin_amdgcn_global_load_lds((const __attribute__((address_space(1))) void*)(W + gB1 + k0),
                                     (__attribute__((address_space(3))) void*)(Bs + c1*8), 16, 0, 0);
    __syncthreads();
    bf16x8 af[2], bfr[4];
    af[0] = *(const bf16x8*)(As + aoff);
    af[1] = *(const bf16x8*)(As + aoff + 16*32);
    #pragma unroll
    for (int nt=0; nt<4; nt++)
      bfr[nt] = *(const bf16x8*)(Bs + boff + nt*16*32);
    #pragma unroll
    for (int mt=0; mt<2; mt++)
      #pragma unroll
      for (int nt=0; nt<4; nt++)
        acc[mt][nt] = __builtin_amdgcn_mfma_f32_16x16x32_bf16(af[mt], bfr[nt], acc[mt][nt], 0, 0, 0);
    __syncthreads();
  }

  float bi[4], sc[4], qc[4];
  #pragma unroll
  for (int nt=0; nt<4; nt++){
    bi[nt] = bias[n0 + wn*64 + nt*16 + (l & 15)];
    sc[nt] = 0.f; qc[nt] = 0.f;
  }
  #pragma unroll
  for (int nt=0; nt<4; nt++){
    const int col = n0 + wn*64 + nt*16 + (l & 15);
    #pragma unroll
    for (int mt=0; mt<2; mt++){
      #pragma unroll
      for (int r=0; r<4; r++){
        const int row = m0 + wm*32 + mt*16 + (l>>4)*4 + r;
        if (row < N_NODES){
          float v = acc[mt][nt][r] + bi[nt];
          v = v > 0.f ? v : 0.f;
          sc[nt] += v; qc[nt] += v*v;
          Hout[(size_t)row*KDIM + HDIM + col] = f2bf(v);
        }
      }
    }
  }
  #pragma unroll
  for (int nt=0; nt<4; nt++){
    float s = sc[nt], q = qc[nt];
    s += __shfl_xor(s, 16); s += __shfl_xor(s, 32);
    q += __shfl_xor(q, 16); q += __shfl_xor(q, 32);
    if (l < 16){
      red_s[wm][wn*64 + nt*16 + l] = s;
      red_q[wm][wn*64 + nt*16 + l] = q;
    }
  }
  __syncthreads();
  if (t < 128){
    atomicAdd(&stats[n0 + t],       red_s[0][t] + red_s[1][t]);
    atomicAdd(&stats[512 + n0 + t], red_q[0][t] + red_q[1][t]);
  }
}

extern "C" void kernel_launch(void* const* d_in, const int* in_sizes, int n_in,
                              void* d_out, int out_size, void* d_ws, size_t ws_size,
                              hipStream_t stream){
  (void)in_sizes; (void)n_in; (void)out_size; (void)ws_size;
  const float* x     = (const float*)d_in[0];
  const int*   eidx  = (const int*)d_in[1];
  const float* wpr   = (const float*)d_in[2];
  const float* wpo   = (const float*)d_in[3];
  const float* wrel  = (const float*)d_in[4];
  const float* wroot = (const float*)d_in[5];
  const float* gamma = (const float*)d_in[6];
  const float* beta  = (const float*)d_in[7];
  const float* wfr   = (const float*)d_in[8];
  const float* wfo   = (const float*)d_in[9];
  const int* src  = eidx;
  const int* dstv = eidx + N_EDGES;

  char* p = (char*)d_ws;
  auto carve = [&](size_t b){ char* q = p; p += (b + 255) & ~(size_t)255; return q; };
  u16*  A0      = (u16*)carve((size_t)NPAD*KDIM*2);
  u16*  A1      = (u16*)carve((size_t)NPAD*KDIM*2);
  u16*  Wcat    = (u16*)carve((size_t)4*HDIM*KDIM*2);
  u16*  Wfin    = (u16*)carve((size_t)10*KDIM*2);
  u16*  Wsc     = (u16*)carve((size_t)HDIM*KDIM*2);
  int*   zreg   = (int*)carve((size_t)NZERO*4);
  int*   cnt    = zreg;
  float* stats  = (float*)(zreg + 10048);
  float* bias0  = (float*)(zreg + 10048 + 4096);
  int*  row_ptr = (int*)carve((N_NODES+1)*4);
  int*  cursor  = (int*)carve(N_NODES*4);
  int*  csr     = (int*)carve(N_EDGES*4);
  float* inv_deg= (float*)carve(N_NODES*4);
  float* biasN  = (float*)carve(512*4);
  float* outp   = (float*)d_out;

  k_prep<<<9154, 256, 0, stream>>>(wpr, wpo, wrel, wroot, wfr, wfo, x, Wcat, Wfin, A0, (u32*)zreg);
  k_hist<<<(N_EDGES+255)/256, 256, 0, stream>>>(dstv, cnt);
  k_scan<<<1, 1024, 0, stream>>>(cnt, row_ptr, cursor, inv_deg);
  k_fill<<<(N_EDGES+255)/256, 256, 0, stream>>>(src, dstv, cursor, csr);
  k_agg<<<N_NODES/2, 256, 0, stream>>>(A0, row_ptr, cnt, csr, inv_deg, A0);

  u16* Ain = A0; u16* Aout = A1;
  for (int lyr=0; lyr<4; lyr++){
    const u16* Wthis = (lyr==0) ? Wcat : Wsc;
    const float* bthis = (lyr==0) ? bias0 : biasN;
    k_gemm<<<NTILES, 256, 0, stream>>>(Ain, Wthis, bthis, Aout, stats + lyr*1024);
    if (lyr < 3){
      k_aggws<<<N_NODES/2, 256, 0, stream>>>(Aout, row_ptr, cnt, csr, inv_deg, Aout,
                                             Wcat + (size_t)(lyr+1)*HDIM*KDIM, stats + lyr*1024,
                                             gamma, beta, lyr, Wsc, biasN);
    } else {
      k_aggfinal<<<N_NODES/2, 256, 0, stream>>>(Aout, row_ptr, cnt, csr, inv_deg,
                                                Wfin, stats + lyr*1024, gamma, beta, outp);
    }
    u16* tmp = Ain; Ain = Aout; Aout = tmp;
  }
}